// Round 3
// baseline (361.623 us; speedup 1.0000x reference)
//
#include <hip/hip_runtime.h>

#define INPUT 32
#define HIDDEN 64
#define BATCH 4096
#define SEQ 256

typedef __attribute__((ext_vector_type(8))) short bf16x8;   // 8 bf16 (4 VGPRs)
typedef __attribute__((ext_vector_type(4))) float floatx4;  // 4 fp32

#define MFMA(a, b, c) __builtin_amdgcn_mfma_f32_16x16x32_bf16((a), (b), (c), 0, 0, 0)

// RNE f32->bf16 scalar (setup-only).
__device__ __forceinline__ unsigned short f2bf(float f) {
    unsigned u = __float_as_uint(f);
    u += 0x7fffu + ((u >> 16) & 1u);
    return (unsigned short)(u >> 16);
}
__device__ __forceinline__ float bf2f(unsigned short b) {
    return __uint_as_float(((unsigned)b) << 16);
}
__device__ __forceinline__ void split8(const float f[8], bf16x8& hi, bf16x8& lo) {
#pragma unroll
    for (int j = 0; j < 8; ++j) {
        unsigned short h = f2bf(f[j]);
        hi[j] = (short)h;
        lo[j] = (short)f2bf(f[j] - bf2f(h));
    }
}

// Truncation split of a pair -> packed hi/lo words (6 VALU). Used for x.
__device__ __forceinline__ void packpair(float f0, float f1, unsigned& hw, unsigned& lw) {
    unsigned b0 = __float_as_uint(f0), b1 = __float_as_uint(f1);
    float h0 = __uint_as_float(b0 & 0xffff0000u);
    float h1 = __uint_as_float(b1 & 0xffff0000u);
    float l0 = f0 - h0, l1 = f1 - h1;
    hw = __builtin_amdgcn_perm(b1, b0, 0x07060302u);
    lw = __builtin_amdgcn_perm(__float_as_uint(l1), __float_as_uint(l0), 0x07060302u);
}

// RNE pack of a pair (recurrent state: accuracy matters).
__device__ __forceinline__ unsigned pack_rne(float f0, float f1) {
    unsigned r0 = __float_as_uint(f0);
    r0 += 0x7fffu + ((r0 >> 16) & 1u);
    unsigned r1 = __float_as_uint(f1);
    r1 += 0x7fffu + ((r1 >> 16) & 1u);
    return __builtin_amdgcn_perm(r1, r0, 0x07060302u);
}

union FragU { bf16x8 v; unsigned u[4]; };

__device__ __forceinline__ void pack8(float4 a, float4 b, FragU& H, FragU& L) {
    packpair(a.x, a.y, H.u[0], L.u[0]);
    packpair(a.z, a.w, H.u[1], L.u[1]);
    packpair(b.x, b.y, H.u[2], L.u[2]);
    packpair(b.z, b.w, H.u[3], L.u[3]);
}

// Round-15: r12/r14 post-mortem — the per-step wall (~1330 cyc) was the
// 4-wave barrier'd LDS h-exchange (write->barrier->read, ~120cy LDS latency
// each way + wave skew), NOT register pressure (r14: VGPR 68->48, slower).
// This round removes the exchange entirely: ONE wave owns 16 chains with the
// full 64x64 Whh, via a hidden-index relabeling that makes the MFMA D-output
// registers bit-identical to the next step's B-operand fragments:
//   D layout: row m=4qd+r, col n=ln.  B layout: k=8qd+j (+32/frag), n=ln.
//   Relabel p(f,qd,j) = 16*(2f+(j>>2)) + 4qd + (j&3): lane (ln,qd) after
//   computing m-tiles 0..3 holds exactly the 16 h values its B-frags need.
//   The permutation is absorbed into Whh's COLUMN order at load time:
//   A-frag (mt, f): cols [32f+4qd,+4) and [32f+16+4qd,+4) of row 16mt+ln
//   (two float4s). W_ih / x / biases / W_fc stay in natural order; D rows
//   are natural (16mt+4qd+r), so bbv/wfc load at offset 16mt+4qd.
// Loop has NO LDS ops and NO barriers. 28 MFMA/step (same FLOPs as r12's
// 4 waves combined). h state = 2 bf16x8 (RNE hi-plane, with Whh lo-plane
// depth-2 correction chain — same numerics as r12 per row).
// Grid: 256 blocks x 64 threads = 1 wave/CU; __launch_bounds__(64,1) ->
// 512-VGPR budget, the 4-deep x register ring cannot spill.
__global__ __launch_bounds__(64, 1) void rnn_sw_kernel(
    const float* __restrict__ x,     // [B, T, 32]
    const float* __restrict__ W_ih,  // [64, 32]
    const float* __restrict__ W_hh,  // [64, 64]
    const float* __restrict__ b_ih,  // [64]
    const float* __restrict__ b_hh,  // [64]
    const float* __restrict__ W_fc,  // [1, 64]
    const float* __restrict__ b_fc,  // [1]
    float* __restrict__ out)         // [B, 1]
{
    const int lane = threadIdx.x & 63;
    const int ln   = lane & 15;       // batch column within group
    const int qd   = lane >> 4;
    const int b0   = blockIdx.x * 16;

    // ---- Weights (A-operands), hi/lo split; Whh columns permuted ----
    bf16x8 WhhH[4][2], WhhL[4][2], WihH[4], WihL[4];
    floatx4 bbv[4];
#pragma unroll
    for (int mt = 0; mt < 4; ++mt) {
        float f[8];
        const float* rh = W_hh + (mt * 16 + ln) * HIDDEN;
#pragma unroll
        for (int fT = 0; fT < 2; ++fT) {
            *(float4*)&f[0] = *(const float4*)(rh + fT * 32 + qd * 4);
            *(float4*)&f[4] = *(const float4*)(rh + fT * 32 + 16 + qd * 4);
            split8(f, WhhH[mt][fT], WhhL[mt][fT]);
        }
        const float* ri = W_ih + (mt * 16 + ln) * INPUT + qd * 8;
        *(float4*)&f[0] = *(const float4*)ri;
        *(float4*)&f[4] = *(const float4*)(ri + 4);
        split8(f, WihH[mt], WihL[mt]);

        float4 bi = *(const float4*)(b_ih + mt * 16 + qd * 4);
        float4 bh = *(const float4*)(b_hh + mt * 16 + qd * 4);
        bbv[mt][0] = bi.x + bh.x; bbv[mt][1] = bi.y + bh.y;
        bbv[mt][2] = bi.z + bh.z; bbv[mt][3] = bi.w + bh.w;
    }

    const float* xp = x + (size_t)(b0 + ln) * (SEQ * INPUT) + qd * 8;

    // ---- Prologue: ihacc = ih(x_0); x ring holds x_1..x_4 ----
    floatx4 ihacc[4];
    {
        float4 a0 = *(const float4*)(xp);
        float4 a1 = *(const float4*)(xp + 4);
        FragU H, L;
        pack8(a0, a1, H, L);
#pragma unroll
        for (int mt = 0; mt < 4; ++mt) {
            ihacc[mt] = MFMA(WihH[mt], H.v, bbv[mt]);
            ihacc[mt] = MFMA(WihH[mt], L.v, ihacc[mt]);
            ihacc[mt] = MFMA(WihL[mt], H.v, ihacc[mt]);
        }
    }
    float4 xa[4], xb[4];
#pragma unroll
    for (int s = 1; s < 4; ++s) {           // slot s <- x_s  (s = t mod 4)
        xa[s] = *(const float4*)(xp + s * INPUT);
        xb[s] = *(const float4*)(xp + s * INPUT + 4);
    }
    xa[0] = *(const float4*)(xp + 4 * INPUT);   // slot 0 <- x_4
    xb[0] = *(const float4*)(xp + 4 * INPUT + 4);

    bf16x8 g0 = {0, 0, 0, 0, 0, 0, 0, 0};   // h_{-1} = 0 (bf16 0x0000)
    bf16x8 g1 = {0, 0, 0, 0, 0, 0, 0, 0};

    floatx4 d[4];   // h_t (f32, natural rows 16mt+4qd+r); live after loop

#pragma unroll 1
    for (int tb = 0; tb < SEQ; tb += 4) {
#pragma unroll
        for (int s = 0; s < 4; ++s) {
            const int t = tb + s;
            const int k = (t + 1) & 3;

            // Off-path: x_{t+1} from ring; refill slot with x_{t+5}.
            float4 ra = xa[k], rb = xb[k];
            const int tn = (t + 5 < SEQ) ? t + 5 : SEQ - 1;
            xa[k] = *(const float4*)(xp + tn * INPUT);
            xb[k] = *(const float4*)(xp + tn * INPUT + 4);
            FragU nH, nL;
            pack8(ra, rb, nH, nL);
            floatx4 ihn[4];
#pragma unroll
            for (int mt = 0; mt < 4; ++mt) {
                ihn[mt] = MFMA(WihH[mt], nH.v, bbv[mt]);
                ihn[mt] = MFMA(WihH[mt], nL.v, ihn[mt]);
                ihn[mt] = MFMA(WihL[mt], nH.v, ihn[mt]);
            }

            // Critical path: hh depth-2 hi chain + parallel depth-2 lo chain
            // (same numerics as r12), then tanh.
#pragma unroll
            for (int mt = 0; mt < 4; ++mt) {
                floatx4 a = MFMA(WhhH[mt][0], g0, ihacc[mt]);
                a = MFMA(WhhH[mt][1], g1, a);
                floatx4 c = {0.f, 0.f, 0.f, 0.f};
                c = MFMA(WhhL[mt][0], g0, c);
                c = MFMA(WhhL[mt][1], g1, c);
#pragma unroll
                for (int r = 0; r < 4; ++r) {
                    float p = a[r] + c[r];
                    float e = __expf(2.0f * p);
                    d[mt][r] = 1.0f - 2.0f * __builtin_amdgcn_rcpf(e + 1.0f);
                }
            }

            // D -> B-frag pack (relabeled space): frag f = [d[2f], d[2f+1]].
            FragU G0, G1;
            G0.u[0] = pack_rne(d[0][0], d[0][1]);
            G0.u[1] = pack_rne(d[0][2], d[0][3]);
            G0.u[2] = pack_rne(d[1][0], d[1][1]);
            G0.u[3] = pack_rne(d[1][2], d[1][3]);
            G1.u[0] = pack_rne(d[2][0], d[2][1]);
            G1.u[1] = pack_rne(d[2][2], d[2][3]);
            G1.u[2] = pack_rne(d[3][0], d[3][1]);
            G1.u[3] = pack_rne(d[3][2], d[3][3]);
            g0 = G0.v;
            g1 = G1.v;

#pragma unroll
            for (int mt = 0; mt < 4; ++mt) ihacc[mt] = ihn[mt];
        }
    }

    // ---- Head: out[b] = sum_p Wfc[p] h[p][b] + b_fc ----
    float acc = 0.f;
#pragma unroll
    for (int mt = 0; mt < 4; ++mt) {
        float4 wf = *(const float4*)(W_fc + mt * 16 + qd * 4);
        acc += wf.x * d[mt][0] + wf.y * d[mt][1] +
               wf.z * d[mt][2] + wf.w * d[mt][3];
    }
    acc += __shfl_xor(acc, 16, 64);
    acc += __shfl_xor(acc, 32, 64);
    if (lane < 16) out[b0 + lane] = acc + b_fc[0];
}

extern "C" void kernel_launch(void* const* d_in, const int* in_sizes, int n_in,
                              void* d_out, int out_size, void* d_ws, size_t ws_size,
                              hipStream_t stream) {
    const float* x    = (const float*)d_in[0];
    const float* W_ih = (const float*)d_in[1];
    const float* W_hh = (const float*)d_in[2];
    const float* b_ih = (const float*)d_in[3];
    const float* b_hh = (const float*)d_in[4];
    const float* W_fc = (const float*)d_in[5];
    const float* b_fc = (const float*)d_in[6];
    float* out = (float*)d_out;

    // 256 independent 16-chain groups: 1 wave each, spread 1 per CU.
    rnn_sw_kernel<<<dim3(BATCH / 16), dim3(64), 0, stream>>>(
        x, W_ih, W_hh, b_ih, b_hh, W_fc, b_fc, out);
}

// Round 4
// 292.274 us; speedup vs baseline: 1.2373x; 1.2373x over previous
//
#include <hip/hip_runtime.h>

#define INPUT 32
#define HIDDEN 64
#define BATCH 4096
#define SEQ 256

typedef __attribute__((ext_vector_type(8))) short bf16x8;   // 8 bf16 (4 VGPRs)
typedef __attribute__((ext_vector_type(4))) float floatx4;  // 4 fp32

#define MFMA(a, b, c) __builtin_amdgcn_mfma_f32_16x16x32_bf16((a), (b), (c), 0, 0, 0)

// LDS-only barrier: wait LDS ops, leave global loads in flight.
#define LDS_BARRIER() asm volatile("s_waitcnt lgkmcnt(0)\n\ts_barrier" ::: "memory")

// RNE f32->bf16 scalar (setup-only).
__device__ __forceinline__ unsigned short f2bf(float f) {
    unsigned u = __float_as_uint(f);
    u += 0x7fffu + ((u >> 16) & 1u);
    return (unsigned short)(u >> 16);
}
__device__ __forceinline__ float bf2f(unsigned short b) {
    return __uint_as_float(((unsigned)b) << 16);
}
__device__ __forceinline__ void split8(const float f[8], bf16x8& hi, bf16x8& lo) {
#pragma unroll
    for (int j = 0; j < 8; ++j) {
        unsigned short h = f2bf(f[j]);
        hi[j] = (short)h;
        lo[j] = (short)f2bf(f[j] - bf2f(h));
    }
}

// Truncation split of a pair -> packed hi/lo words (6 VALU). Used for x.
__device__ __forceinline__ void packpair(float f0, float f1, unsigned& hw, unsigned& lw) {
    unsigned b0 = __float_as_uint(f0), b1 = __float_as_uint(f1);
    float h0 = __uint_as_float(b0 & 0xffff0000u);
    float h1 = __uint_as_float(b1 & 0xffff0000u);
    float l0 = f0 - h0, l1 = f1 - h1;
    hw = __builtin_amdgcn_perm(b1, b0, 0x07060302u);
    lw = __builtin_amdgcn_perm(__float_as_uint(l1), __float_as_uint(l0), 0x07060302u);
}

// RNE pack of a pair (recurrent state: accuracy matters).
__device__ __forceinline__ unsigned pack_rne(float f0, float f1) {
    unsigned r0 = __float_as_uint(f0);
    r0 += 0x7fffu + ((r0 >> 16) & 1u);
    unsigned r1 = __float_as_uint(f1);
    r1 += 0x7fffu + ((r1 >> 16) & 1u);
    return __builtin_amdgcn_perm(r1, r0, 0x07060302u);
}

union FragU { bf16x8 v; unsigned u[4]; };

__device__ __forceinline__ void pack8(float4 a, float4 b, FragU& H, FragU& L) {
    packpair(a.x, a.y, H.u[0], L.u[0]);
    packpair(a.z, a.w, H.u[1], L.u[1]);
    packpair(b.x, b.y, H.u[2], L.u[2]);
    packpair(b.z, b.w, H.u[3], L.u[3]);
}

// Round-16: r15 (1 wave, no exchange) = 2030 cyc/step, pure issue-serialization
// (one in-order wave must issue ~850cy/step of work + unfillable stalls).
// r12 (4 waves) = 1330 cyc/step, exchange (b64 write + barrier + 2x b128 read
// + 4-wave skew) fully on the critical path. Optimum in between:
// TWO waves, wave w owns hidden rows [32w,32w+32) = m-tiles {2w,2w+1}.
// With 16x16x32 MFMA a B-frag spans k=32 = exactly one wave's rows, so the
// HW-PROVEN relabeling (r15, bit-identical absmax) makes wave w's packed
// D-outputs literally B-frag g_w in registers:
//   - own-half hh MFMA starts with ZERO exchange latency;
//   - exchange = ONE ds_write_b128 + ONE ds_read_b128 (vs r12's 1W+2R),
//     double-buffered, one 2-wave barrier/step;
//   - foreign MFMA is 2nd in the accum chain: LDS read latency hides under
//     own-half MFMAs + 6 ihn MFMAs issued in between;
//   - per-wave issue ~450cy (14 MFMA, 8 exp+8 rcp, x-pack) ~= path length.
// Numerics: same packpair/pack_rne/tanh/lo-correction math as r12/r15.
// Wave 1 accumulates frag1 before frag0 (reordered f32 sum) -> absmax may
// shift slightly from 0.00390625; threshold 0.0206 has 5x margin.
// Layouts (HW-verified r5-r15): C/D row=4qd+r col=ln; A m=ln k=8qd+j;
//   B n=ln k=8qd+j(+32/frag). Relabel sigma(32f+8qd+j)=32f+16(j>>2)+4qd+(j&3)
//   absorbed into Whh column order: frag f cols [32f+4qd,+4),[32f+16+4qd,+4).
// Exchange LDS (u16): buf*1024 + frag*512 + lane*8  (buf = t&1).
__global__ __launch_bounds__(128, 1) void rnn_dw_kernel(
    const float* __restrict__ x,     // [B, T, 32]
    const float* __restrict__ W_ih,  // [64, 32]
    const float* __restrict__ W_hh,  // [64, 64]
    const float* __restrict__ b_ih,  // [64]
    const float* __restrict__ b_hh,  // [64]
    const float* __restrict__ W_fc,  // [1, 64]
    const float* __restrict__ b_fc,  // [1]
    float* __restrict__ out)         // [B, 1]
{
    const int tid  = threadIdx.x;
    const int w    = tid >> 6;        // wave id: owns frag w (rows 32w..32w+31)
    const int lane = tid & 63;
    const int ln   = lane & 15;       // batch column
    const int qd   = lane >> 4;
    const int b0   = blockIdx.x * 16;

    __shared__ __align__(16) unsigned short Hs[2048];  // 4 KB: 2 bufs x 2 frags
    __shared__ float Ps[32];

    // ---- Weights (A-operands) for THIS wave's 2 tiles; Whh cols permuted ----
    bf16x8 WhhH[2][2], WhhL[2][2], WihH[2], WihL[2];
    floatx4 bbv[2];
#pragma unroll
    for (int m = 0; m < 2; ++m) {
        const int mt = 2 * w + m;
        float f[8];
        const float* rh = W_hh + (mt * 16 + ln) * HIDDEN;
#pragma unroll
        for (int fT = 0; fT < 2; ++fT) {
            *(float4*)&f[0] = *(const float4*)(rh + fT * 32 + qd * 4);
            *(float4*)&f[4] = *(const float4*)(rh + fT * 32 + 16 + qd * 4);
            split8(f, WhhH[m][fT], WhhL[m][fT]);
        }
        const float* ri = W_ih + (mt * 16 + ln) * INPUT + qd * 8;
        *(float4*)&f[0] = *(const float4*)ri;
        *(float4*)&f[4] = *(const float4*)(ri + 4);
        split8(f, WihH[m], WihL[m]);

        float4 bi = *(const float4*)(b_ih + mt * 16 + qd * 4);
        float4 bh = *(const float4*)(b_hh + mt * 16 + qd * 4);
        bbv[m][0] = bi.x + bh.x; bbv[m][1] = bi.y + bh.y;
        bbv[m][2] = bi.z + bh.z; bbv[m][3] = bi.w + bh.w;
    }

    const float* xp = x + (size_t)(b0 + ln) * (SEQ * INPUT) + qd * 8;

    // ---- Prologue: ihacc = ih(x_0); x ring holds x_1..x_4 ----
    floatx4 ihacc[2];
    {
        float4 a0 = *(const float4*)(xp);
        float4 a1 = *(const float4*)(xp + 4);
        FragU H, L;
        pack8(a0, a1, H, L);
#pragma unroll
        for (int m = 0; m < 2; ++m) {
            ihacc[m] = MFMA(WihH[m], H.v, bbv[m]);
            ihacc[m] = MFMA(WihH[m], L.v, ihacc[m]);
            ihacc[m] = MFMA(WihL[m], H.v, ihacc[m]);
        }
    }
    float4 xa[4], xb[4];
#pragma unroll
    for (int s = 1; s < 4; ++s) {           // slot s <- x_s  (s = t mod 4)
        xa[s] = *(const float4*)(xp + s * INPUT);
        xb[s] = *(const float4*)(xp + s * INPUT + 4);
    }
    xa[0] = *(const float4*)(xp + 4 * INPUT);   // slot 0 <- x_4
    xb[0] = *(const float4*)(xp + 4 * INPUT + 4);

    bf16x8 g_own = {0, 0, 0, 0, 0, 0, 0, 0};   // own frag of h_{-1} = 0

    floatx4 d[2];   // this wave's h rows (f32); live after loop for the head

    // Exchange bases (u16 units): write own frag, read partner's.
    unsigned short* const wr0 = Hs + w * 512 + lane * 8;
    const unsigned short* const rd0 = Hs + (1 - w) * 512 + lane * 8;

#pragma unroll 1
    for (int tb = 0; tb < SEQ; tb += 4) {
#pragma unroll
        for (int s = 0; s < 4; ++s) {
            const int t = tb + s;
            const int k = (t + 1) & 3;
            const int buf = (t & 1) << 10;

            // Publish own frag of h_{t-1} into buf (b128, linear, no swizzle).
            *(bf16x8*)(wr0 + buf) = g_own;

            // Own-half hh starts immediately: zero exchange latency.
            floatx4 a0 = MFMA(WhhH[0][w], g_own, ihacc[0]);
            floatx4 a1 = MFMA(WhhH[1][w], g_own, ihacc[1]);
            floatx4 zero = {0.f, 0.f, 0.f, 0.f};
            floatx4 c0 = MFMA(WhhL[0][w], g_own, zero);
            floatx4 c1 = MFMA(WhhL[1][w], g_own, zero);

            // Off-path x work (covers ds_write latency / MFMA pipe busy):
            // x_{t+1} from ring; refill slot with x_{t+5}; pack.
            float4 ra = xa[k], rb = xb[k];
            const int tn = (t + 5 < SEQ) ? t + 5 : SEQ - 1;
            xa[k] = *(const float4*)(xp + tn * INPUT);
            xb[k] = *(const float4*)(xp + tn * INPUT + 4);
            FragU nH, nL;
            pack8(ra, rb, nH, nL);

            LDS_BARRIER();   // own write drained; partner's write visible.

            // Foreign frag (ONE b128 read); latency covered by ihn MFMAs.
            bf16x8 g_for = *(const bf16x8*)(rd0 + buf);

            floatx4 ihn[2];
#pragma unroll
            for (int m = 0; m < 2; ++m) {
                ihn[m] = MFMA(WihH[m], nH.v, bbv[m]);
                ihn[m] = MFMA(WihH[m], nL.v, ihn[m]);
                ihn[m] = MFMA(WihL[m], nH.v, ihn[m]);
            }

            // Foreign-half hh (2nd in the accumulation chains).
            a0 = MFMA(WhhH[0][1 - w], g_for, a0);
            a1 = MFMA(WhhH[1][1 - w], g_for, a1);
            c0 = MFMA(WhhL[0][1 - w], g_for, c0);
            c1 = MFMA(WhhL[1][1 - w], g_for, c1);

            // tanh of this wave's 8 elements.
#pragma unroll
            for (int r = 0; r < 4; ++r) {
                float p = a0[r] + c0[r];
                float e = __expf(2.0f * p);
                d[0][r] = 1.0f - 2.0f * __builtin_amdgcn_rcpf(e + 1.0f);
            }
#pragma unroll
            for (int r = 0; r < 4; ++r) {
                float p = a1[r] + c1[r];
                float e = __expf(2.0f * p);
                d[1][r] = 1.0f - 2.0f * __builtin_amdgcn_rcpf(e + 1.0f);
            }

            // D -> own B-frag (relabeled space): slots = [d0, d1].
            FragU G;
            G.u[0] = pack_rne(d[0][0], d[0][1]);
            G.u[1] = pack_rne(d[0][2], d[0][3]);
            G.u[2] = pack_rne(d[1][0], d[1][1]);
            G.u[3] = pack_rne(d[1][2], d[1][3]);
            g_own = G.v;

            ihacc[0] = ihn[0];
            ihacc[1] = ihn[1];
        }
    }

    // ---- Head: out[b] = sum_p Wfc[p] h[p][b] + b_fc ----
    float acc = 0.f;
#pragma unroll
    for (int m = 0; m < 2; ++m) {
        float4 wf = *(const float4*)(W_fc + (2 * w + m) * 16 + qd * 4);
        acc += wf.x * d[m][0] + wf.y * d[m][1] +
               wf.z * d[m][2] + wf.w * d[m][3];
    }
    acc += __shfl_xor(acc, 16, 64);
    acc += __shfl_xor(acc, 32, 64);
    if (lane < 16) Ps[w * 16 + lane] = acc;
    __syncthreads();
    if (tid < 16) out[b0 + tid] = Ps[tid] + Ps[16 + tid] + b_fc[0];
}

extern "C" void kernel_launch(void* const* d_in, const int* in_sizes, int n_in,
                              void* d_out, int out_size, void* d_ws, size_t ws_size,
                              hipStream_t stream) {
    const float* x    = (const float*)d_in[0];
    const float* W_ih = (const float*)d_in[1];
    const float* W_hh = (const float*)d_in[2];
    const float* b_ih = (const float*)d_in[3];
    const float* b_hh = (const float*)d_in[4];
    const float* W_fc = (const float*)d_in[5];
    const float* b_fc = (const float*)d_in[6];
    float* out = (float*)d_out;

    // 256 groups of 16 chains: 2 waves each (one group per CU).
    rnn_dw_kernel<<<dim3(BATCH / 16), dim3(128), 0, stream>>>(
        x, W_ih, W_hh, b_ih, b_hh, W_fc, b_fc, out);
}